// Round 8
// baseline (2687.541 us; speedup 1.0000x reference)
//
#include <hip/hip_runtime.h>

typedef __attribute__((ext_vector_type(8))) short short8;   // 8 bf16 in 4 VGPRs
typedef __attribute__((ext_vector_type(4))) float f32x4;
typedef __attribute__((ext_vector_type(4))) unsigned int u32x4;
typedef __attribute__((ext_vector_type(2))) unsigned int u32x2;
typedef unsigned short u16;
typedef unsigned int u32;

static constexpr int TT = 512;
static constexpr int HDim = 1024;
static constexpr int NBH = 64 * 1024;          // B*HD = 65536
static constexpr int NBLK = 64;                // 4 bg (16 rows) x 16 hg (64 h)
static constexpr int VBUF = 65536;             // u32 per V buffer: 64 rows*512 pairs*{pay,tag}

__device__ __forceinline__ u16 f2bf(float f) {             // RNE f32->bf16
  u32 u = __float_as_uint(f);
  u32 r = u + 0x7FFFu + ((u >> 16) & 1u);
  return (u16)(r >> 16);
}
__device__ __forceinline__ float bf2f(u16 u) {
  return __uint_as_float(((u32)u) << 16);
}
__device__ __forceinline__ float sigmoidf_(float v) {
  return 1.0f / (1.0f + __expf(-v));
}

#define WAITVM(n) asm volatile("s_waitcnt vmcnt(" #n ")" ::: "memory")
#define SBAR() __builtin_amdgcn_sched_barrier(0)
// non-rematerializable weight load (plain cache path; long-lived regs)
#define WLD(dst, p) asm volatile("global_load_dwordx4 %0, %1, off" : "=v"(dst) : "v"(p))
// agent-coherent (sc1) ops: L3 is the coherence point across XCDs
#define PLD(dst, p) asm volatile("global_load_dwordx4 %0, %1, off sc1" : "=v"(dst) : "v"(p) : "memory")
#define PLD2(dst, p) asm volatile("global_load_dwordx2 %0, %1, off sc1" : "=v"(dst) : "v"(p) : "memory")
#define PST2(p, v2) asm volatile("global_store_dwordx2 %0, %1, off sc1" :: "v"(p), "v"(v2) : "memory")
#define MFMA(a, b, c) __builtin_amdgcn_mfma_f32_16x16x32_bf16(a, b, c, 0, 0, 0)

// ------- prep: Wih->bf16; V0 slots {pay,tag=0} in buf0; buf1 tags=~0 -------
__global__ void prep_kernel(const float* __restrict__ x, const float* __restrict__ Q0,
                            const float* __restrict__ Wih, const float* __restrict__ uVr,
                            const float* __restrict__ uV2,
                            u16* __restrict__ Wih_bf, u32* __restrict__ Vpt) {
  const int NW = 2048 * 1024;
  int stride = gridDim.x * blockDim.x;
  int gid = blockIdx.x * blockDim.x + threadIdx.x;
  for (int i = gid; i < NW; i += stride) Wih_bf[i] = f2bf(Wih[i]);
  for (int p = gid; p < 32768; p += stride) {          // 64 rows x 512 k-pairs
    int s = p * 2;                                     // u32 slot base = row*1024 + 2*kp
    int h0 = s & 1023;
    float g0 = sigmoidf_(uV2[h0]) * tanhf(uVr[h0]);
    float g1 = sigmoidf_(uV2[h0 + 1]) * tanhf(uVr[h0 + 1]);
    u32 pay = (u32)f2bf(x[s] + g0 * Q0[s]) |
              ((u32)f2bf(x[s + 1] + g1 * Q0[s + 1]) << 16);
    Vpt[s] = pay;            Vpt[s + 1] = 0u;          // V_0, tag 0
    Vpt[VBUF + s] = 0u;      Vpt[VBUF + s + 1] = 0xFFFFFFFFu;  // buf1 invalid
  }
}

// ---------------- A_all = x @ WA^T  (M=32768,N=1024,K=1024), bf16 out ------
__global__ __launch_bounds__(256) void agemm_kernel(const float* __restrict__ X,
                                                    const float* __restrict__ W,
                                                    u16* __restrict__ C) {
  __shared__ u16 As[128 * 64];
  __shared__ u16 Bs[128 * 64];
  int tid = threadIdx.x;
  int l = tid & 63, w = tid >> 6;
  int n = l & 15, rowg = l >> 4;
  int wr = w >> 1, wc = w & 1;
  int bm = blockIdx.x >> 3, bn = blockIdx.x & 7;
  long m0 = (long)bm * 128;
  int n0 = bn * 128;
  int srow = tid >> 4;
  int sk4 = (tid & 15) * 4;

  f32x4 acc[4][4];
#pragma unroll
  for (int r = 0; r < 4; ++r)
#pragma unroll
    for (int c = 0; c < 4; ++c) acc[r][c] = (f32x4){0.f, 0.f, 0.f, 0.f};

  for (int kt = 0; kt < 16; ++kt) {
    __syncthreads();
#pragma unroll
    for (int i = 0; i < 8; ++i) {
      int row = srow + i * 16;
      float4 va = *(const float4*)(X + (m0 + row) * 1024 + kt * 64 + sk4);
      u32 lo = (u32)f2bf(va.x) | ((u32)f2bf(va.y) << 16);
      u32 hi = (u32)f2bf(va.z) | ((u32)f2bf(va.w) << 16);
      *(uint2*)(As + row * 64 + sk4) = make_uint2(lo, hi);
      float4 vb = *(const float4*)(W + (long)(n0 + row) * 1024 + kt * 64 + sk4);
      u32 lo2 = (u32)f2bf(vb.x) | ((u32)f2bf(vb.y) << 16);
      u32 hi2 = (u32)f2bf(vb.z) | ((u32)f2bf(vb.w) << 16);
      *(uint2*)(Bs + row * 64 + sk4) = make_uint2(lo2, hi2);
    }
    __syncthreads();
#pragma unroll
    for (int ks = 0; ks < 2; ++ks) {
      short8 af[4], bfr[4];
#pragma unroll
      for (int r = 0; r < 4; ++r)
        af[r] = *(const short8*)(As + (wr * 64 + r * 16 + n) * 64 + ks * 32 + rowg * 8);
#pragma unroll
      for (int c = 0; c < 4; ++c)
        bfr[c] = *(const short8*)(Bs + (wc * 64 + c * 16 + n) * 64 + ks * 32 + rowg * 8);
#pragma unroll
      for (int r = 0; r < 4; ++r)
#pragma unroll
        for (int c = 0; c < 4; ++c)
          acc[r][c] = __builtin_amdgcn_mfma_f32_16x16x32_bf16(af[r], bfr[c], acc[r][c], 0, 0, 0);
    }
  }
#pragma unroll
  for (int r = 0; r < 4; ++r)
#pragma unroll
    for (int c = 0; c < 4; ++c)
#pragma unroll
      for (int q = 0; q < 4; ++q) {
        long row = m0 + wr * 64 + r * 16 + rowg * 4 + q;
        int col = n0 + wc * 64 + c * 16 + n;
        C[row * 1024 + col] = f2bf(acc[r][c][q]);
      }
}

// ---------------- persistent scan ------------------------------------------
// 64 blocks = 4 bg (16 rows) x 16 hg (64 h), 512 thr = 8 waves, K-split 128/wave.
// V slots {pay(2 bf16), tag=t} via one dwordx2 sc1 (no drain, no flags).
// Sync: wave 0 spins on 16 canary slots (0.5 KB/iter, 128x less than full
// sweep), barrier, then ONE tagged full sweep (self-validating, rare retry).
__global__ __launch_bounds__(512, 1)
void scan_kernel(const u16* __restrict__ Wih_bf, const u16* __restrict__ A_bf,
                 const float* __restrict__ x, const float* __restrict__ S0,
                 const float* __restrict__ PFB, const float* __restrict__ HWb,
                 const float* __restrict__ uVr, const float* __restrict__ uV2,
                 u32* __restrict__ Vpt, float* __restrict__ out) {
  __shared__ f32x4 red[2][8][8][64];           // [t&1][j-tile][wave][lane] 128KB
  const int tid = threadIdx.x, bk = blockIdx.x;
  const int bg = bk >> 4, hg = bk & 15;
  const int l = tid & 63, w = tid >> 6;
  const int n = l & 15, rowg = l >> 4, hl = n & 7;
  const bool isF = (n < 8);
  const int h = hg * 64 + w * 8 + hl;          // wave w's output h (post-reduce)

  // weights: 8 j-tiles x 4 k-slices = 32 short8 = 128 regs, asm-pinned
  short8 bw[8][4];
  {
    const int fOff = isF ? 0 : HDim;
#pragma unroll
    for (int jt = 0; jt < 8; ++jt) {
      const u16* wp = Wih_bf + (long)(fOff + hg * 64 + jt * 8 + hl) * 1024 + w * 128 + rowg * 8;
      WLD(bw[jt][0], wp);      WLD(bw[jt][1], wp + 32);
      WLD(bw[jt][2], wp + 64); WLD(bw[jt][3], wp + 96);
    }
  }
  WAITVM(0); SBAR();

  const float pfb = PFB[h], hwb = HWb[h];
  const float gh = sigmoidf_(uV2[h]) * tanhf(uVr[h]);

  const int row0 = bg * 16 + rowg * 4;
  int rowoff[4];
  float S[4];
#pragma unroll
  for (int r = 0; r < 4; ++r) { rowoff[r] = (row0 + r) * 1024 + h; S[r] = S0[rowoff[r]]; }

  // sweep/A-frag base: row = bg*16 + n, k = w*128 + s*32 + rowg*8 (+e)
  const u32* pbase = Vpt + (bg * 16 + n) * 1024 + w * 128 + rowg * 8;
  // canary: slot (row=bg*16, h=hg'*64) written by producer hg' (w=0,hl=0,r=0 lane)
  const u32* cbase = Vpt + bg * 16 * 1024 + (l & 15) * 64;

  float xq[4], xn[4], av[4], Qs[4];
#pragma unroll
  for (int r = 0; r < 4; ++r) {
    xq[r] = x[rowoff[r]];
    xn[r] = x[NBH + rowoff[r]];
    av[r] = bf2f(A_bf[rowoff[r]]);
  }

#pragma unroll 1
  for (int t = 0; t < TT; ++t) {
    const u32 tv = (u32)t;
    const int half = (t & 1);

    // ---- canary gate: wave 0 spins on 16 producers' first slots
    if (w == 0) {
      const u32* cb = cbase + half * VBUF;
      while (true) {
        u32x2 cv;
        PLD2(cv, cb);
        WAITVM(0); SBAR();
        if (__all(cv[1] == tv)) break;
      }
    }
    __syncthreads();

    // ---- deferred Y stores from previous step (drain under compute)
    if (t > 0) {
      const long pvbase = (long)(t - 1) * NBH;
#pragma unroll
      for (int r = 0; r < 4; ++r)
        if (isF) out[pvbase + rowoff[r]] = Qs[r];
    }

    // ---- ONE tagged data sweep (tags self-validate; retry is rare)
    const u32* pb = pbase + half * VBUF;
    u32x4 q0a, q0b, q1a, q1b, q2a, q2b, q3a, q3b;
    while (true) {
      PLD(q0a, pb);      PLD(q0b, pb + 4);
      PLD(q1a, pb + 32); PLD(q1b, pb + 36);
      PLD(q2a, pb + 64); PLD(q2b, pb + 68);
      PLD(q3a, pb + 96); PLD(q3b, pb + 100);
      WAITVM(0); SBAR();
      bool ok = (q0a[1] == tv) & (q0a[3] == tv) & (q0b[1] == tv) & (q0b[3] == tv)
              & (q1a[1] == tv) & (q1a[3] == tv) & (q1b[1] == tv) & (q1b[3] == tv)
              & (q2a[1] == tv) & (q2a[3] == tv) & (q2b[1] == tv) & (q2b[3] == tv)
              & (q3a[1] == tv) & (q3a[3] == tv) & (q3b[1] == tv) & (q3b[3] == tv);
      if (__all(ok)) break;
    }

    // ---- extract payloads -> A fragments; MFMA (data already in regs)
    u32x4 p0 = {q0a[0], q0a[2], q0b[0], q0b[2]};
    u32x4 p1 = {q1a[0], q1a[2], q1b[0], q1b[2]};
    u32x4 p2 = {q2a[0], q2a[2], q2b[0], q2b[2]};
    u32x4 p3 = {q3a[0], q3a[2], q3b[0], q3b[2]};
    short8 va0 = __builtin_bit_cast(short8, p0);
    short8 va1 = __builtin_bit_cast(short8, p1);
    short8 va2 = __builtin_bit_cast(short8, p2);
    short8 va3 = __builtin_bit_cast(short8, p3);

    f32x4 pa[8];
#pragma unroll
    for (int jt = 0; jt < 8; ++jt) pa[jt] = (f32x4){0.f, 0.f, 0.f, 0.f};
#pragma unroll
    for (int jt = 0; jt < 8; ++jt) pa[jt] = MFMA(va0, bw[jt][0], pa[jt]);
#pragma unroll
    for (int jt = 0; jt < 8; ++jt) pa[jt] = MFMA(va1, bw[jt][1], pa[jt]);
#pragma unroll
    for (int jt = 0; jt < 8; ++jt) pa[jt] = MFMA(va2, bw[jt][2], pa[jt]);
#pragma unroll
    for (int jt = 0; jt < 8; ++jt) pa[jt] = MFMA(va3, bw[jt][3], pa[jt]);

    // ---- cross-wave K-reduction (double-buffered: one barrier per step)
#pragma unroll
    for (int jt = 0; jt < 8; ++jt) red[half][jt][w][l] = pa[jt];
    __syncthreads();
    f32x4 fr = red[half][w][0][l] + red[half][w][1][l] + red[half][w][2][l] + red[half][w][3][l]
             + red[half][w][4][l] + red[half][w][5][l] + red[half][w][6][l] + red[half][w][7][l];

    // ---- gates, state update, tagged V stores (fire-and-forget)
    u32* vnext = Vpt + ((t + 1) & 1) * VBUF;
    const long tbase = (long)t * NBH;
#pragma unroll
    for (int r = 0; r < 4; ++r) {
      float mine = fr[r];
      float other = __shfl_xor(mine, 8, 64);
      float Fi = isF ? mine : other;
      float Ri = isF ? other : mine;
      float F = sigmoidf_(Fi + pfb);
      float Rg = sigmoidf_(Ri + hwb);
      S[r] = F * S[r] + (1.0f - F) * av[r];
      float Q = Rg * S[r] + (1.0f - Rg) * xq[r];
      Qs[r] = Q;
      if (t < TT - 1) {
        u32 word = (u32)f2bf(xn[r] + gh * Q);
        u32 othw = (u32)__shfl_xor((int)word, 1, 64);
        if (isF && (hl & 1) == 0) {
          u32x2 pv = {word | (othw << 16), (u32)(t + 1)};
          PST2(vnext + rowoff[r], pv);          // {pay, tag} in one 8B store
        }
      }
    }

    if (t == TT - 1) {
#pragma unroll
      for (int r = 0; r < 4; ++r)
        if (isF) {
          out[tbase + rowoff[r]] = Qs[r];
          out[(long)TT * NBH + rowoff[r]] = Qs[r];            // Qf
          out[(long)TT * NBH + NBH + rowoff[r]] = S[r];       // Sf
        }
      break;
    }

    // ---- prefetch next step's scalars (in flight across the next canary)
    const long nb = tbase + NBH;
    const int tn = (t + 2 < TT) ? (t + 2) : (TT - 1);
    const long nb2 = (long)tn * NBH;
#pragma unroll
    for (int r = 0; r < 4; ++r) {
      xq[r] = x[nb + rowoff[r]];
      av[r] = bf2f(A_bf[nb + rowoff[r]]);
      xn[r] = x[nb2 + rowoff[r]];
    }
  }
}

extern "C" void kernel_launch(void* const* d_in, const int* in_sizes, int n_in,
                              void* d_out, int out_size, void* d_ws, size_t ws_size,
                              hipStream_t stream) {
  const float* x   = (const float*)d_in[0];
  const float* Q0  = (const float*)d_in[1];
  const float* S0  = (const float*)d_in[2];
  const float* Wih = (const float*)d_in[3];
  const float* WA  = (const float*)d_in[4];
  const float* uVr = (const float*)d_in[5];
  const float* uV2 = (const float*)d_in[6];
  const float* PFB = (const float*)d_in[7];
  const float* HWb = (const float*)d_in[8];
  float* out = (float*)d_out;

  char* ws = (char*)d_ws;
  u16* A_bf   = (u16*)(ws);                 // 67,108,864 B : A_all bf16 [T*B][HD]
  u16* Wih_bf = (u16*)(ws + 67108864);      //  4,194,304 B
  u32* Vpt    = (u32*)(ws + 71303168);      //    524,288 B : ping-pong {pay,tag}
  (void)in_sizes; (void)n_in; (void)out_size; (void)ws_size;

  prep_kernel<<<2048, 256, 0, stream>>>(x, Q0, Wih, uVr, uV2, Wih_bf, Vpt);
  agemm_kernel<<<2048, 256, 0, stream>>>(x, WA, A_bf);
  scan_kernel<<<NBLK, 512, 0, stream>>>(Wih_bf, A_bf, x, S0, PFB, HWb, uVr, uV2, Vpt, out);
}

// Round 9
// 2383.862 us; speedup vs baseline: 1.1274x; 1.1274x over previous
//
#include <hip/hip_runtime.h>

typedef __attribute__((ext_vector_type(8))) short short8;   // 8 bf16 in 4 VGPRs
typedef __attribute__((ext_vector_type(4))) float f32x4;
typedef __attribute__((ext_vector_type(4))) unsigned int u32x4;
typedef unsigned short u16;
typedef unsigned int u32;

static constexpr int TT = 512;
static constexpr int HDim = 1024;
static constexpr int NBH = 64 * 1024;          // B*HD = 65536
static constexpr int NBLK = 64;                // 4 bg (16 rows) x 16 hg (64 h)

__device__ __forceinline__ u16 f2bf(float f) {             // RNE f32->bf16
  u32 u = __float_as_uint(f);
  u32 r = u + 0x7FFFu + ((u >> 16) & 1u);
  return (u16)(r >> 16);
}
__device__ __forceinline__ float bf2f(u16 u) {
  return __uint_as_float(((u32)u) << 16);
}
__device__ __forceinline__ float sigmoidf_(float v) {
  return 1.0f / (1.0f + __expf(-v));
}

#define WAITVM(n) asm volatile("s_waitcnt vmcnt(" #n ")" ::: "memory")
#define SBAR() __builtin_amdgcn_sched_barrier(0)
// non-rematerializable weight load (plain cache path; long-lived regs)
#define WLD(dst, p) asm volatile("global_load_dwordx4 %0, %1, off" : "=v"(dst) : "v"(p))
// agent-coherent (sc1) ops: L3 is the coherence point across XCDs
#define PLD(dst, p) asm volatile("global_load_dwordx4 %0, %1, off sc1" : "=v"(dst) : "v"(p) : "memory")
#define LOAD_U32_SC1(dst, p) asm volatile("global_load_dword %0, %1, off sc1" : "=v"(dst) : "v"(p) : "memory")
#define ST4_SC1(p, v) asm volatile("global_store_dword %0, %1, off sc1" :: "v"(p), "v"(v) : "memory")
#define ST16_SC1(p, v4) asm volatile("global_store_dwordx4 %0, %1, off sc1" :: "v"(p), "v"(v4) : "memory")
#define MFMA(a, b, c) __builtin_amdgcn_mfma_f32_16x16x32_bf16(a, b, c, 0, 0, 0)

// ------- prep: Wih->bf16; V0 into buf0; flags zero -------------------------
__global__ void prep_kernel(const float* __restrict__ x, const float* __restrict__ Q0,
                            const float* __restrict__ Wih, const float* __restrict__ uVr,
                            const float* __restrict__ uV2,
                            u16* __restrict__ Wih_bf, u16* __restrict__ Vws,
                            u32* __restrict__ flags) {
  const int NW = 2048 * 1024;
  int stride = gridDim.x * blockDim.x;
  int gid = blockIdx.x * blockDim.x + threadIdx.x;
  if (gid < 1024) flags[gid] = 0u;             // 64 flags @ 64B stride
  for (int i = gid; i < NW; i += stride) Wih_bf[i] = f2bf(Wih[i]);
  for (int j = gid; j < NBH; j += stride) {
    int h = j & (HDim - 1);
    float g = sigmoidf_(uV2[h]) * tanhf(uVr[h]);
    Vws[j] = f2bf(x[j] + g * Q0[j]);           // V_0 in buf0
  }
}

// ---------------- A_all = x @ WA^T  (M=32768,N=1024,K=1024), bf16 out ------
__global__ __launch_bounds__(256) void agemm_kernel(const float* __restrict__ X,
                                                    const float* __restrict__ W,
                                                    u16* __restrict__ C) {
  __shared__ u16 As[128 * 64];
  __shared__ u16 Bs[128 * 64];
  int tid = threadIdx.x;
  int l = tid & 63, w = tid >> 6;
  int n = l & 15, rowg = l >> 4;
  int wr = w >> 1, wc = w & 1;
  int bm = blockIdx.x >> 3, bn = blockIdx.x & 7;
  long m0 = (long)bm * 128;
  int n0 = bn * 128;
  int srow = tid >> 4;
  int sk4 = (tid & 15) * 4;

  f32x4 acc[4][4];
#pragma unroll
  for (int r = 0; r < 4; ++r)
#pragma unroll
    for (int c = 0; c < 4; ++c) acc[r][c] = (f32x4){0.f, 0.f, 0.f, 0.f};

  for (int kt = 0; kt < 16; ++kt) {
    __syncthreads();
#pragma unroll
    for (int i = 0; i < 8; ++i) {
      int row = srow + i * 16;
      float4 va = *(const float4*)(X + (m0 + row) * 1024 + kt * 64 + sk4);
      u32 lo = (u32)f2bf(va.x) | ((u32)f2bf(va.y) << 16);
      u32 hi = (u32)f2bf(va.z) | ((u32)f2bf(va.w) << 16);
      *(uint2*)(As + row * 64 + sk4) = make_uint2(lo, hi);
      float4 vb = *(const float4*)(W + (long)(n0 + row) * 1024 + kt * 64 + sk4);
      u32 lo2 = (u32)f2bf(vb.x) | ((u32)f2bf(vb.y) << 16);
      u32 hi2 = (u32)f2bf(vb.z) | ((u32)f2bf(vb.w) << 16);
      *(uint2*)(Bs + row * 64 + sk4) = make_uint2(lo2, hi2);
    }
    __syncthreads();
#pragma unroll
    for (int ks = 0; ks < 2; ++ks) {
      short8 af[4], bfr[4];
#pragma unroll
      for (int r = 0; r < 4; ++r)
        af[r] = *(const short8*)(As + (wr * 64 + r * 16 + n) * 64 + ks * 32 + rowg * 8);
#pragma unroll
      for (int c = 0; c < 4; ++c)
        bfr[c] = *(const short8*)(Bs + (wc * 64 + c * 16 + n) * 64 + ks * 32 + rowg * 8);
#pragma unroll
      for (int r = 0; r < 4; ++r)
#pragma unroll
        for (int c = 0; c < 4; ++c)
          acc[r][c] = __builtin_amdgcn_mfma_f32_16x16x32_bf16(af[r], bfr[c], acc[r][c], 0, 0, 0);
    }
  }
#pragma unroll
  for (int r = 0; r < 4; ++r)
#pragma unroll
    for (int c = 0; c < 4; ++c)
#pragma unroll
      for (int q = 0; q < 4; ++q) {
        long row = m0 + wr * 64 + r * 16 + rowg * 4 + q;
        int col = n0 + wc * 64 + c * 16 + n;
        C[row * 1024 + col] = f2bf(acc[r][c][q]);
      }
}

// ---------------- persistent scan ------------------------------------------
// 64 blocks = 4 bg (16 rows) x 16 hg (64 h), 512 thr = 8 waves, K-split 128/wave.
// r5 protocol (per-wave drain + block join + single flag) with per-wave
// dataflow: wave w needs k in [128w,128w+128) -> polls ONLY producers
// hg'=2w,2w+1 (2 flags, 128 B/iter) and starts its MFMAs immediately.
__global__ __launch_bounds__(512, 1)
void scan_kernel(const u16* __restrict__ Wih_bf, const u16* __restrict__ A_bf,
                 const float* __restrict__ x, const float* __restrict__ S0,
                 const float* __restrict__ PFB, const float* __restrict__ HWb,
                 const float* __restrict__ uVr, const float* __restrict__ uV2,
                 u16* __restrict__ Vws, float* __restrict__ out,
                 u32* __restrict__ flags) {
  __shared__ f32x4 red[8][8][64];              // [j-tile][wave][lane] 64 KB
  const int tid = threadIdx.x, bk = blockIdx.x;
  const int bg = bk >> 4, hg = bk & 15;
  const int l = tid & 63, w = tid >> 6;
  const int n = l & 15, rowg = l >> 4, hl = n & 7;
  const bool isF = (n < 8);
  const int h = hg * 64 + w * 8 + hl;          // wave w's output h (post-reduce)

  // weights: 8 j-tiles x 4 k-slices = 32 short8 = 128 regs, asm-pinned
  short8 bw[8][4];
  {
    const int fOff = isF ? 0 : HDim;
#pragma unroll
    for (int jt = 0; jt < 8; ++jt) {
      const u16* wp = Wih_bf + (long)(fOff + hg * 64 + jt * 8 + hl) * 1024 + w * 128 + rowg * 8;
      WLD(bw[jt][0], wp);      WLD(bw[jt][1], wp + 32);
      WLD(bw[jt][2], wp + 64); WLD(bw[jt][3], wp + 96);
    }
  }
  WAITVM(0); SBAR();

  const float pfb = PFB[h], hwb = HWb[h];
  const float gh = sigmoidf_(uV2[h]) * tanhf(uVr[h]);

  const int row0 = bg * 16 + rowg * 4;
  int rowoff[4];
  float S[4];
#pragma unroll
  for (int r = 0; r < 4; ++r) { rowoff[r] = (row0 + r) * 1024 + h; S[r] = S0[rowoff[r]]; }

  // frag base: row = bg*16 + n, k = w*128 + s*32 + rowg*8 (+e)
  const u16* vb0 = Vws + (bg * 16 + n) * 1024 + w * 128 + rowg * 8;
  // my wave's 2 producer flags: hg' = 2w + (l&1)
  const u32* fp = flags + ((bg * 16 + 2 * w + (l & 1)) << 4);

  float xq[4], xn[4], av[4], Qs[4];
#pragma unroll
  for (int r = 0; r < 4; ++r) {
    xq[r] = x[rowoff[r]];
    xn[r] = x[NBH + rowoff[r]];
    av[r] = bf2f(A_bf[rowoff[r]]);
  }
  WAITVM(0); SBAR();

#pragma unroll 1
  for (int t = 0; t < TT; ++t) {
    const u32 tv = (u32)t;
    // ---- per-wave poll: my 2 producers reached step t (128 B/iter)
    if (t > 0) {
      while (true) {
        u32 fv;
        LOAD_U32_SC1(fv, fp);
        WAITVM(0); SBAR();
        if (__all(fv >= tv)) break;
      }
    }

    // ---- frag loads (sc1), counted waits overlap with MFMA
    const u16* pb = vb0 + (t & 1) * NBH;
    short8 va0, va1, va2, va3;
    PLD(va0, pb); PLD(va1, pb + 32); PLD(va2, pb + 64); PLD(va3, pb + 96);

    f32x4 pa[8];
#pragma unroll
    for (int jt = 0; jt < 8; ++jt) pa[jt] = (f32x4){0.f, 0.f, 0.f, 0.f};
    WAITVM(3); SBAR();
#pragma unroll
    for (int jt = 0; jt < 8; ++jt) pa[jt] = MFMA(va0, bw[jt][0], pa[jt]);
    WAITVM(2); SBAR();
#pragma unroll
    for (int jt = 0; jt < 8; ++jt) pa[jt] = MFMA(va1, bw[jt][1], pa[jt]);
    WAITVM(1); SBAR();
#pragma unroll
    for (int jt = 0; jt < 8; ++jt) pa[jt] = MFMA(va2, bw[jt][2], pa[jt]);
    WAITVM(0); SBAR();
#pragma unroll
    for (int jt = 0; jt < 8; ++jt) pa[jt] = MFMA(va3, bw[jt][3], pa[jt]);

    // ---- deferred Y stores from previous step (ack during reduce/gates)
    if (t > 0) {
      const long pvbase = (long)(t - 1) * NBH;
#pragma unroll
      for (int r = 0; r < 4; ++r)
        if (isF) out[pvbase + rowoff[r]] = Qs[r];
    }

    // ---- cross-wave K-reduction (single buffer; bar2 protects reuse)
#pragma unroll
    for (int jt = 0; jt < 8; ++jt) red[jt][w][l] = pa[jt];
    __syncthreads();
    f32x4 fr = red[w][0][l] + red[w][1][l] + red[w][2][l] + red[w][3][l]
             + red[w][4][l] + red[w][5][l] + red[w][6][l] + red[w][7][l];

    // ---- gates, state update
    const long tbase = (long)t * NBH;
    u32 pk[4];
#pragma unroll
    for (int r = 0; r < 4; ++r) {
      float mine = fr[r];
      float other = __shfl_xor(mine, 8, 64);
      float Fi = isF ? mine : other;
      float Ri = isF ? other : mine;
      float F = sigmoidf_(Fi + pfb);
      float Rg = sigmoidf_(Ri + hwb);
      S[r] = F * S[r] + (1.0f - F) * av[r];
      float Q = Rg * S[r] + (1.0f - Rg) * xq[r];
      Qs[r] = Q;
      u32 word = (u32)f2bf(xn[r] + gh * Q);
      u32 othw = (u32)__shfl_xor((int)word, 1, 64);
      pk[r] = word | (othw << 16);             // (h,h+1) pack, valid on even hl
    }

    if (t == TT - 1) {
#pragma unroll
      for (int r = 0; r < 4; ++r)
        if (isF) {
          out[tbase + rowoff[r]] = Qs[r];
          out[(long)TT * NBH + rowoff[r]] = Qs[r];            // Qf
          out[(long)TT * NBH + NBH + rowoff[r]] = S[r];       // Sf
        }
      break;
    }

    // ---- V stores: shuffle-pack to one dwordx4 per row on n==0 lanes
    {
      u16* vnext = Vws + ((t + 1) & 1) * NBH;
#pragma unroll
      for (int r = 0; r < 4; ++r) {
        u32 pB = (u32)__shfl_xor((int)pk[r], 2, 64);   // lane0 <- hl2 (h2,h3)
        u32 pC = (u32)__shfl_xor((int)pk[r], 4, 64);   // lane0 <- hl4 (h4,h5)
        u32 pD = (u32)__shfl_xor((int)pB, 4, 64);      // lane0 <- hl6 (h6,h7)
        if (n == 0) {
          u32x4 v4 = {pk[r], pB, pC, pD};
          ST16_SC1(vnext + (row0 + r) * 1024 + hg * 64 + w * 8, v4);
        }
      }
    }

    // ---- drain (V stores + earlier Y stores), block join, signal
    WAITVM(0);
    __syncthreads();
    if (tid == 0) ST4_SC1(flags + (bk << 4), tv + 1u);

    // ---- prefetch next step's scalars (complete during next poll)
    const long nb = tbase + NBH;
    const int tn = (t + 2 < TT) ? (t + 2) : (TT - 1);
    const long nb2 = (long)tn * NBH;
#pragma unroll
    for (int r = 0; r < 4; ++r) {
      xq[r] = x[nb + rowoff[r]];
      av[r] = bf2f(A_bf[nb + rowoff[r]]);
      xn[r] = x[nb2 + rowoff[r]];
    }
  }
}

extern "C" void kernel_launch(void* const* d_in, const int* in_sizes, int n_in,
                              void* d_out, int out_size, void* d_ws, size_t ws_size,
                              hipStream_t stream) {
  const float* x   = (const float*)d_in[0];
  const float* Q0  = (const float*)d_in[1];
  const float* S0  = (const float*)d_in[2];
  const float* Wih = (const float*)d_in[3];
  const float* WA  = (const float*)d_in[4];
  const float* uVr = (const float*)d_in[5];
  const float* uV2 = (const float*)d_in[6];
  const float* PFB = (const float*)d_in[7];
  const float* HWb = (const float*)d_in[8];
  float* out = (float*)d_out;

  char* ws = (char*)d_ws;
  u16* A_bf   = (u16*)(ws);                 // 67,108,864 B : A_all bf16 [T*B][HD]
  u16* Wih_bf = (u16*)(ws + 67108864);      //  4,194,304 B
  u16* Vws    = (u16*)(ws + 71303168);      //    262,144 B : ping-pong V (bf16)
  u32* flags  = (u32*)(ws + 71565312);      //      4,096 B : 64 flags @64B stride
  (void)in_sizes; (void)n_in; (void)out_size; (void)ws_size;

  prep_kernel<<<2048, 256, 0, stream>>>(x, Q0, Wih, uVr, uV2, Wih_bf, Vws, flags);
  agemm_kernel<<<2048, 256, 0, stream>>>(x, WA, A_bf);
  scan_kernel<<<NBLK, 512, 0, stream>>>(Wih_bf, A_bf, x, S0, PFB, HWb, uVr, uV2, Vws, out, flags);
}